// Round 2
// baseline (58708.942 us; speedup 1.0000x reference)
//
#include <hip/hip_runtime.h>
#include <hip/hip_bf16.h>
#include <cstdint>
#include <cstddef>

#define D    768
#define G3   2304
#define BS   64
#define SEQ  300
#define TDEC 100

typedef unsigned int u32;

__device__ __forceinline__ float sigf(float x) { return 1.0f / (1.0f + __expf(-x)); }
__device__ __forceinline__ float tanhfast(float x) {
    float e = __expf(2.0f * x);
    return 1.0f - 2.0f / (e + 1.0f);
}
__device__ __forceinline__ void bf2x(u32 u, float& a, float& b) {
    union { u32 i; float f; } xx, yy;
    xx.i = u << 16; yy.i = u & 0xffff0000u; a = xx.f; b = yy.f;
}

#define DOT4(acc, wv, x0, x1, x2, x3) \
    acc = fmaf((wv).x,(x0), fmaf((wv).y,(x1), fmaf((wv).z,(x2), fmaf((wv).w,(x3),(acc)))))

// grid barrier: monotone counter. All grids <= 256 blocks x 256 thr, <=34KB LDS
// -> 1 block/CU ALWAYS co-resident (VGPR<=512 always true) -> no deadlock.
__device__ __forceinline__ void gridbar(u32* cnt, u32& target, u32 nblk) {
    __syncthreads();
    target += nblk;
    if (threadIdx.x == 0) {
        __threadfence();
        atomicAdd(cnt, 1u);
        while (__hip_atomic_load(cnt, __ATOMIC_RELAXED, __HIP_MEMORY_SCOPE_AGENT) < target)
            __builtin_amdgcn_s_sleep(2);
        __threadfence();
    }
    __syncthreads();
}

// ---------------- kPrep: PE table, dec_Wih split, zero h0/cnt ----------------
__global__ __launch_bounds__(256) void kPrep(
    const float* __restrict__ decWih,
    float* __restrict__ peT, float* __restrict__ Wc, float* __restrict__ W0,
    float* __restrict__ hT0, u32* __restrict__ cnt)
{
    const int NP = SEQ * D;          // 230400
    const int NW = G3 * 769;         // 1771776
    const int TOT = NP + NW + D * 64 + 64;
    const int stride = gridDim.x * blockDim.x;
    for (int u = blockIdx.x * blockDim.x + threadIdx.x; u < TOT; u += stride) {
        if (u < NP) {
            int k = u % D; int s = u / D;
            int i = k >> 1;
            float dv  = __expf(-0.0239852614f * (float)i);   // exp(2i * -ln(1e4)/768)
            float ang = (float)s * dv;
            peT[u] = (k & 1) ? __cosf(ang) : __sinf(ang);
        } else if (u < NP + NW) {
            int v = u - NP; int g = v / 769; int c = v % 769;
            float w = decWih[v];
            if (c == 0) W0[g] = w; else Wc[(size_t)g * D + (c - 1)] = w;
        } else if (u < NP + NW + D * 64) {
            hT0[u - NP - NW] = 0.0f;
        } else {
            cnt[u - NP - NW - D * 64] = 0u;
        }
    }
}

// ---------------- kEnc: persistent encoder GRU (192 blocks) ----------------
// thread: b = tid&63, j = blk*4 + (tid>>6). h stored [k][b].
__global__ __launch_bounds__(256) void kEnc(
    const float* __restrict__ x, const float* __restrict__ peT,
    const float* __restrict__ Wih, const float* __restrict__ Whh,
    const float* __restrict__ bih, const float* __restrict__ bhh,
    float* __restrict__ hT0, float* __restrict__ hT1,
    __hip_bfloat16* __restrict__ encB, u32* __restrict__ cnt)
{
    __shared__ float lds_a[64 * 65];   // [b][k+pad]: conflict-free lds_a[b*65+kk]
    __shared__ float lds_h[64 * 64];   // [kk][b]
    const int tid = threadIdx.x;
    const int b   = tid & 63;
    const int jw  = __builtin_amdgcn_readfirstlane((int)(blockIdx.x * 4 + (tid >> 6)));

    const float* wir = Wih + (size_t)jw * D;
    const float* wiz = Wih + (size_t)(768 + jw) * D;
    const float* win = Wih + (size_t)(1536 + jw) * D;
    const float* whr = Whh + (size_t)jw * D;
    const float* whz = Whh + (size_t)(768 + jw) * D;
    const float* whn = Whh + (size_t)(1536 + jw) * D;
    const float bir = bih[jw], biz = bih[768 + jw], bin_ = bih[1536 + jw];
    const float bhr = bhh[jw], bhz = bhh[768 + jw], bhn  = bhh[1536 + jw];

    u32 target = 0;
    for (int t = 0; t < SEQ; ++t) {
        const float* hrd = (t & 1) ? hT1 : hT0;
        float*       hwr = (t & 1) ? hT0 : hT1;

        float air = 0.f, aiz = 0.f, ain = 0.f, ahr = 0.f, ahz = 0.f, ahn = 0.f;
        for (int kc = 0; kc < D; kc += 64) {
            // stage x-tile (row-major in x) into transposed padded LDS; add PE
            #pragma unroll
            for (int it = 0; it < 4; ++it) {
                const int idx = tid + 256 * it;
                const int row = idx >> 4, c4 = (idx & 15) * 4;
                const float4 xa = *(const float4*)(x + ((size_t)row * SEQ + t) * D + kc + c4);
                const float4 pe = *(const float4*)(peT + (size_t)t * D + kc + c4);
                const int la = row * 65 + c4;
                lds_a[la + 0] = xa.x + pe.x; lds_a[la + 1] = xa.y + pe.y;
                lds_a[la + 2] = xa.z + pe.z; lds_a[la + 3] = xa.w + pe.w;
            }
            const float4* gh = (const float4*)(hrd + kc * 64);
            float4* lh = (float4*)lds_h;
            #pragma unroll
            for (int it = 0; it < 4; ++it) lh[tid + 256 * it] = gh[tid + 256 * it];
            __syncthreads();
            #pragma unroll
            for (int kk = 0; kk < 64; kk += 4) {
                const float4 v0 = *(const float4*)(wir + kc + kk);
                const float4 v1 = *(const float4*)(wiz + kc + kk);
                const float4 v2 = *(const float4*)(win + kc + kk);
                const float4 v3 = *(const float4*)(whr + kc + kk);
                const float4 v4 = *(const float4*)(whz + kc + kk);
                const float4 v5 = *(const float4*)(whn + kc + kk);
                const float a0 = lds_a[b * 65 + kk + 0];
                const float a1 = lds_a[b * 65 + kk + 1];
                const float a2 = lds_a[b * 65 + kk + 2];
                const float a3 = lds_a[b * 65 + kk + 3];
                const float h0 = lds_h[(kk + 0) * 64 + b];
                const float h1 = lds_h[(kk + 1) * 64 + b];
                const float h2 = lds_h[(kk + 2) * 64 + b];
                const float h3 = lds_h[(kk + 3) * 64 + b];
                DOT4(air, v0, a0, a1, a2, a3);
                DOT4(aiz, v1, a0, a1, a2, a3);
                DOT4(ain, v2, a0, a1, a2, a3);
                DOT4(ahr, v3, h0, h1, h2, h3);
                DOT4(ahz, v4, h0, h1, h2, h3);
                DOT4(ahn, v5, h0, h1, h2, h3);
            }
            __syncthreads();
        }
        const float r = sigf(air + bir + ahr + bhr);
        const float z = sigf(aiz + biz + ahz + bhz);
        const float n = tanhfast(ain + bin_ + r * (ahn + bhn));
        const float ho = hrd[jw * 64 + b];
        const float hn = (1.f - z) * n + z * ho;
        hwr[jw * 64 + b] = hn;
        encB[((size_t)b * SEQ + t) * D + jw] = __float2bfloat16(hn);
        gridbar(cnt, target, 192);
    }
}

// ---------------- kGemmMem: mem = enc @ mW^T + mb  (bf16 A, fp32 B, bf16 out) ----------------
__global__ __launch_bounds__(256) void kGemmMem(
    const __hip_bfloat16* __restrict__ encB, const float* __restrict__ mW,
    const float* __restrict__ mb, __hip_bfloat16* __restrict__ memB)
{
    __shared__ float As[16 * 64];
    __shared__ float Bs[16 * 64];
    const int tid = threadIdx.x;
    const int m0 = blockIdx.y * 64, n0 = blockIdx.x * 64;
    const int lr = tid >> 2;
    const int lk = (tid & 3) * 4;
    const int tm = (tid >> 4) * 4;
    const int tn = (tid & 15) * 4;

    float acc[4][4];
    #pragma unroll
    for (int i = 0; i < 4; ++i)
        #pragma unroll
        for (int j = 0; j < 4; ++j) acc[i][j] = 0.f;

    for (int kc = 0; kc < D; kc += 16) {
        const uint2 ua = *(const uint2*)(encB + (size_t)(m0 + lr) * D + kc + lk);
        float a0, a1, a2, a3;
        bf2x(ua.x, a0, a1); bf2x(ua.y, a2, a3);
        const float4 b4 = *(const float4*)(mW + (size_t)(n0 + lr) * D + kc + lk);
        As[(lk + 0) * 64 + lr] = a0; As[(lk + 1) * 64 + lr] = a1;
        As[(lk + 2) * 64 + lr] = a2; As[(lk + 3) * 64 + lr] = a3;
        Bs[(lk + 0) * 64 + lr] = b4.x; Bs[(lk + 1) * 64 + lr] = b4.y;
        Bs[(lk + 2) * 64 + lr] = b4.z; Bs[(lk + 3) * 64 + lr] = b4.w;
        __syncthreads();
        #pragma unroll
        for (int k = 0; k < 16; ++k) {
            const float4 av = *(const float4*)(As + k * 64 + tm);
            const float4 bv = *(const float4*)(Bs + k * 64 + tn);
            acc[0][0] = fmaf(av.x, bv.x, acc[0][0]); acc[0][1] = fmaf(av.x, bv.y, acc[0][1]);
            acc[0][2] = fmaf(av.x, bv.z, acc[0][2]); acc[0][3] = fmaf(av.x, bv.w, acc[0][3]);
            acc[1][0] = fmaf(av.y, bv.x, acc[1][0]); acc[1][1] = fmaf(av.y, bv.y, acc[1][1]);
            acc[1][2] = fmaf(av.y, bv.z, acc[1][2]); acc[1][3] = fmaf(av.y, bv.w, acc[1][3]);
            acc[2][0] = fmaf(av.z, bv.x, acc[2][0]); acc[2][1] = fmaf(av.z, bv.y, acc[2][1]);
            acc[2][2] = fmaf(av.z, bv.z, acc[2][2]); acc[2][3] = fmaf(av.z, bv.w, acc[2][3]);
            acc[3][0] = fmaf(av.w, bv.x, acc[3][0]); acc[3][1] = fmaf(av.w, bv.y, acc[3][1]);
            acc[3][2] = fmaf(av.w, bv.z, acc[3][2]); acc[3][3] = fmaf(av.w, bv.w, acc[3][3]);
        }
        __syncthreads();
    }
    const float bb0 = mb[n0 + tn + 0], bb1 = mb[n0 + tn + 1];
    const float bb2 = mb[n0 + tn + 2], bb3 = mb[n0 + tn + 3];
    #pragma unroll
    for (int i = 0; i < 4; ++i) {
        __hip_bfloat16* row = memB + (size_t)(m0 + tm + i) * D + n0 + tn;
        row[0] = __float2bfloat16(acc[i][0] + bb0);
        row[1] = __float2bfloat16(acc[i][1] + bb1);
        row[2] = __float2bfloat16(acc[i][2] + bb2);
        row[3] = __float2bfloat16(acc[i][3] + bb3);
    }
}

// ---------------- kDec: persistent decoder (256 blocks) ----------------
__global__ __launch_bounds__(256) void kDec(
    const float* __restrict__ qW, const float* __restrict__ qb,
    const __hip_bfloat16* __restrict__ memB, const __hip_bfloat16* __restrict__ encB,
    const float* __restrict__ pW, const float* __restrict__ pb,
    const float* __restrict__ dWhh, const float* __restrict__ Wc, const float* __restrict__ W0,
    const float* __restrict__ dbih, const float* __restrict__ dbhh,
    const float* __restrict__ tW, const float* __restrict__ tb,
    float* __restrict__ hT0, float* __restrict__ hT1,
    float* __restrict__ qbuf, float* __restrict__ ctxP,
    float* __restrict__ seP, float* __restrict__ lastb,
    float* __restrict__ out, u32* __restrict__ cnt)
{
    __shared__ float lds[8448];   // S3: lds_h 4096 + lds_c 4160; S2: ~2.4K
    const int tid = threadIdx.x;
    const int blk = blockIdx.x;
    u32 target = 0;

    // phase 0: decoder h0 = 0, last = 0
    for (int i = blk * 256 + tid; i < D * 64 + 64; i += 256 * 256) {
        if (i < D * 64) hT0[i] = 0.f; else lastb[i - D * 64] = 0.f;
    }
    gridbar(cnt, target, 256);

    for (int t = 0; t <= TDEC; ++t) {
        const float* hrd = (t & 1) ? hT1 : hT0;
        float*       hwr = (t & 1) ? hT0 : hT1;

        // ---- P1: q (blk<192) | pred_{t-1} + last (192..255)
        if (blk < 192) {
            if (t < TDEC) {
                const int b = tid & 63;
                const int jw = __builtin_amdgcn_readfirstlane((int)(blk * 4 + (tid >> 6)));
                const float* w = qW + (size_t)jw * D;
                float acc = 0.f;
                for (int k = 0; k < D; k += 4) {
                    const float4 w4 = *(const float4*)(w + k);
                    acc = fmaf(w4.x, hrd[(k + 0) * 64 + b], acc);
                    acc = fmaf(w4.y, hrd[(k + 1) * 64 + b], acc);
                    acc = fmaf(w4.z, hrd[(k + 2) * 64 + b], acc);
                    acc = fmaf(w4.w, hrd[(k + 3) * 64 + b], acc);
                }
                qbuf[(size_t)b * D + jw] = acc + qb[jw];
            }
        } else {
            if (t >= 1) {
                const int b = blk - 192;
                float p = 0.f;
                for (int dd = tid; dd < D; dd += 256) p = fmaf(tW[dd], hrd[dd * 64 + b], p);
                lds[tid] = p;
                __syncthreads();
                for (int sft = 128; sft > 0; sft >>= 1) {
                    if (tid < sft) lds[tid] += lds[tid + sft];
                    __syncthreads();
                }
                if (tid == 0) {
                    const float pr = lds[0] + tb[0];
                    out[(size_t)b * TDEC + (t - 1)] = pr;
                    lastb[b] = pr;
                }
            }
        }
        gridbar(cnt, target, 256);
        if (t == TDEC) break;

        // ---- S2: attention. block = (ch = blk>>6, b = blk&63), 75 s-rows each
        {
            const int b  = blk & 63;
            const int ch = blk >> 6;
            const int s0 = ch * 75;
            float* s_q  = lds;
            float* s_pw = lds + 768;
            float* s_cx = lds + 1536;
            float* s_se = lds + 2304;
            for (int i = tid; i < 768; i += 256) {
                s_q[i]  = qbuf[(size_t)b * D + i];
                s_pw[i] = pW[i];
                s_cx[i] = 0.f;
            }
            if (tid == 0) s_se[0] = 0.f;
            __syncthreads();
            const int lane = tid & 63;
            const int wv   = tid >> 6;
            float cacc[12];
            #pragma unroll
            for (int i = 0; i < 12; ++i) cacc[i] = 0.f;
            float seacc = 0.f;                     // per-wave sum (same on all lanes)
            const float pbv = pb[0];
            for (int s = s0 + wv; s < s0 + 75; s += 4) {
                const __hip_bfloat16* mrow = memB + ((size_t)b * SEQ + s) * D;
                const __hip_bfloat16* erow = encB + ((size_t)b * SEQ + s) * D;
                float lp = 0.f;
                #pragma unroll
                for (int i = 0; i < 12; ++i) {
                    const int dd = lane + 64 * i;
                    const float mv = __bfloat162float(mrow[dd]);
                    lp = fmaf(s_pw[dd], tanhfast(mv + s_q[dd]), lp);
                }
                #pragma unroll
                for (int o = 32; o > 0; o >>= 1) lp += __shfl_xor(lp, o, 64);
                const float e = __expf(lp + pbv);   // identical on all 64 lanes
                seacc += e;
                #pragma unroll
                for (int i = 0; i < 12; ++i) {
                    const int dd = lane + 64 * i;
                    cacc[i] = fmaf(e, __bfloat162float(erow[dd]), cacc[i]);
                }
            }
            #pragma unroll
            for (int i = 0; i < 12; ++i) atomicAdd(&s_cx[lane + 64 * i], cacc[i]);
            // seacc is already the wave total (all lanes identical) — NO lane reduce
            if (lane == 0) atomicAdd(&s_se[0], seacc);
            __syncthreads();
            float* cp = ctxP + (size_t)ch * (64 * D) + (size_t)b * D;   // [ch][b][k]
            for (int i = tid; i < 768; i += 256) cp[i] = s_cx[i];
            if (tid == 0) seP[ch * 64 + b] = s_se[0];
        }
        gridbar(cnt, target, 256);

        // ---- S3: GRU cell (blk<192)
        if (blk < 192) {
            float* lds_h = lds;            // [kk][b], 4096
            float* lds_c = lds + 4096;     // [b][kk+pad], 64*65
            const int b  = tid & 63;
            const int jw = __builtin_amdgcn_readfirstlane((int)(blk * 4 + (tid >> 6)));
            const float* whr = dWhh + (size_t)jw * D;
            const float* whz = dWhh + (size_t)(768 + jw) * D;
            const float* whn = dWhh + (size_t)(1536 + jw) * D;
            const float* wcr = Wc + (size_t)jw * D;
            const float* wcz = Wc + (size_t)(768 + jw) * D;
            const float* wcn = Wc + (size_t)(1536 + jw) * D;
            float cir = 0.f, ciz = 0.f, cin_ = 0.f, ahr = 0.f, ahz = 0.f, ahn = 0.f;
            for (int kc = 0; kc < D; kc += 64) {
                const float4* gh = (const float4*)(hrd + kc * 64);
                float4* lh = (float4*)lds_h;
                #pragma unroll
                for (int it = 0; it < 4; ++it) lh[tid + 256 * it] = gh[tid + 256 * it];
                #pragma unroll
                for (int it = 0; it < 4; ++it) {
                    const int idx = tid + 256 * it;
                    const int row = idx >> 4, c4 = (idx & 15) * 4;
                    const float* p0 = ctxP + (size_t)row * D + kc + c4;
                    const float4 u0 = *(const float4*)(p0);
                    const float4 u1 = *(const float4*)(p0 + 64 * D);
                    const float4 u2 = *(const float4*)(p0 + 2 * 64 * D);
                    const float4 u3 = *(const float4*)(p0 + 3 * 64 * D);
                    const int la = row * 65 + c4;
                    lds_c[la + 0] = u0.x + u1.x + u2.x + u3.x;
                    lds_c[la + 1] = u0.y + u1.y + u2.y + u3.y;
                    lds_c[la + 2] = u0.z + u1.z + u2.z + u3.z;
                    lds_c[la + 3] = u0.w + u1.w + u2.w + u3.w;
                }
                __syncthreads();
                #pragma unroll
                for (int kk = 0; kk < 64; kk += 4) {
                    const float4 v0 = *(const float4*)(wcr + kc + kk);
                    const float4 v1 = *(const float4*)(wcz + kc + kk);
                    const float4 v2 = *(const float4*)(wcn + kc + kk);
                    const float4 v3 = *(const float4*)(whr + kc + kk);
                    const float4 v4 = *(const float4*)(whz + kc + kk);
                    const float4 v5 = *(const float4*)(whn + kc + kk);
                    const float c0 = lds_c[b * 65 + kk + 0];
                    const float c1 = lds_c[b * 65 + kk + 1];
                    const float c2 = lds_c[b * 65 + kk + 2];
                    const float c3 = lds_c[b * 65 + kk + 3];
                    const float h0 = lds_h[(kk + 0) * 64 + b];
                    const float h1 = lds_h[(kk + 1) * 64 + b];
                    const float h2 = lds_h[(kk + 2) * 64 + b];
                    const float h3 = lds_h[(kk + 3) * 64 + b];
                    DOT4(cir, v0, c0, c1, c2, c3);
                    DOT4(ciz, v1, c0, c1, c2, c3);
                    DOT4(cin_, v2, c0, c1, c2, c3);
                    DOT4(ahr, v3, h0, h1, h2, h3);
                    DOT4(ahz, v4, h0, h1, h2, h3);
                    DOT4(ahn, v5, h0, h1, h2, h3);
                }
                __syncthreads();
            }
            const float se = seP[b] + seP[64 + b] + seP[128 + b] + seP[192 + b];
            const float inv = 1.f / se;
            const float lst = lastb[b];
            const float gir = cir * inv + W0[jw] * lst + dbih[jw];
            const float giz = ciz * inv + W0[768 + jw] * lst + dbih[768 + jw];
            const float gin = cin_ * inv + W0[1536 + jw] * lst + dbih[1536 + jw];
            const float r = sigf(gir + ahr + dbhh[jw]);
            const float z = sigf(giz + ahz + dbhh[768 + jw]);
            const float n = tanhfast(gin + r * (ahn + dbhh[1536 + jw]));
            const float ho = hrd[jw * 64 + b];
            hwr[jw * 64 + b] = (1.f - z) * n + z * ho;
        }
        gridbar(cnt, target, 256);
    }
}

// ---------------- launch ----------------
extern "C" void kernel_launch(void* const* d_in, const int* in_sizes, int n_in,
                              void* d_out, int out_size, void* d_ws, size_t ws_size,
                              hipStream_t stream) {
    const float* x    = (const float*)d_in[0];
    const float* eWih = (const float*)d_in[1];
    const float* eWhh = (const float*)d_in[2];
    const float* ebih = (const float*)d_in[3];
    const float* ebhh = (const float*)d_in[4];
    const float* dWih = (const float*)d_in[5];
    const float* dWhh = (const float*)d_in[6];
    const float* dbih = (const float*)d_in[7];
    const float* dbhh = (const float*)d_in[8];
    const float* qW   = (const float*)d_in[9];
    const float* qb   = (const float*)d_in[10];
    const float* mW   = (const float*)d_in[11];
    const float* mb   = (const float*)d_in[12];
    const float* pW   = (const float*)d_in[13];
    const float* pb   = (const float*)d_in[14];
    const float* tW   = (const float*)d_in[15];
    const float* tb   = (const float*)d_in[16];
    float* out = (float*)d_out;

    char* w = (char*)d_ws;
    auto alloc = [&](size_t bytes) -> char* {
        char* p = w; w += (bytes + 255) & ~(size_t)255; return p;
    };
    // total ~69 MB
    u32*   cnt   = (u32*)  alloc(64 * sizeof(u32));
    float* peT   = (float*)alloc((size_t)SEQ * D * 4);
    float* Wc    = (float*)alloc((size_t)G3 * D * 4);
    float* W0    = (float*)alloc((size_t)G3 * 4);
    __hip_bfloat16* encB = (__hip_bfloat16*)alloc((size_t)BS * SEQ * D * 2);
    __hip_bfloat16* memB = (__hip_bfloat16*)alloc((size_t)BS * SEQ * D * 2);
    float* hT0   = (float*)alloc((size_t)D * 64 * 4);
    float* hT1   = (float*)alloc((size_t)D * 64 * 4);
    float* qbuf  = (float*)alloc((size_t)D * 64 * 4);
    float* ctxP  = (float*)alloc((size_t)4 * 64 * D * 4);
    float* seP   = (float*)alloc(4 * 64 * 4);
    float* lastb = (float*)alloc(64 * 4);

    kPrep<<<256, 256, 0, stream>>>(dWih, peT, Wc, W0, hT0, cnt);
    kEnc<<<192, 256, 0, stream>>>(x, peT, eWih, eWhh, ebih, ebhh, hT0, hT1, encB, cnt + 0);
    kGemmMem<<<dim3(12, 300), 256, 0, stream>>>(encB, mW, mb, memB);
    kDec<<<256, 256, 0, stream>>>(qW, qb, memB, encB, pW, pb, dWhh, Wc, W0, dbih, dbhh,
                                  tW, tb, hT0, hT1, qbuf, ctxP, seP, lastb, out, cnt + 1);
}

// Round 3
// 34582.843 us; speedup vs baseline: 1.6976x; 1.6976x over previous
//
#include <hip/hip_runtime.h>
#include <hip/hip_bf16.h>
#include <cstdint>
#include <cstddef>

#define D    768
#define G3   2304
#define BS   64
#define SEQ  300
#define TDEC 100

typedef unsigned int u32;

__device__ __forceinline__ float sigf(float x) { return 1.0f / (1.0f + __expf(-x)); }
__device__ __forceinline__ float tanhfast(float x) {
    float e = __expf(2.0f * x);
    return 1.0f - 2.0f / (e + 1.0f);
}
__device__ __forceinline__ void bf2x(u32 u, float& a, float& b) {
    union { u32 i; float f; } xx, yy;
    xx.i = u << 16; yy.i = u & 0xffff0000u; a = xx.f; b = yy.f;
}

#define DOT4(acc, wv, x0, x1, x2, x3) \
    acc = fmaf((wv).x,(x0), fmaf((wv).y,(x1), fmaf((wv).z,(x2), fmaf((wv).w,(x3),(acc)))))

// ---------------- kPrep: PE table, dec_Wih split, init h/last/out ----------------
__global__ __launch_bounds__(256) void kPrep(
    const float* __restrict__ decWih, const float* __restrict__ tb,
    float* __restrict__ peT, float* __restrict__ Wc, float* __restrict__ W0,
    float* __restrict__ hE0, float* __restrict__ hD0,
    float* __restrict__ lastP, float* __restrict__ out)
{
    const int NP = SEQ * D;          // 230400
    const int NW = G3 * 769;         // 1771776
    const int NH = D * 64;           // 49152
    const int NL = 101 * 64;
    const int NO = 64 * TDEC;
    const int TOT = NP + NW + 2 * NH + NL + NO;
    const float tbv = tb[0];
    const int stride = gridDim.x * blockDim.x;
    for (int u = blockIdx.x * blockDim.x + threadIdx.x; u < TOT; u += stride) {
        if (u < NP) {
            int k = u % D; int s = u / D;
            int i = k >> 1;
            float dv  = __expf(-0.0239852614f * (float)i);   // exp(2i * -ln(1e4)/768)
            float ang = (float)s * dv;
            peT[u] = (k & 1) ? __cosf(ang) : __sinf(ang);
        } else if (u < NP + NW) {
            int v = u - NP; int g = v / 769; int c = v % 769;
            float w = decWih[v];
            if (c == 0) W0[g] = w; else Wc[(size_t)g * D + (c - 1)] = w;
        } else if (u < NP + NW + NH) {
            hE0[u - NP - NW] = 0.0f;
        } else if (u < NP + NW + 2 * NH) {
            hD0[u - NP - NW - NH] = 0.0f;
        } else if (u < NP + NW + 2 * NH + NL) {
            int i = u - NP - NW - 2 * NH;
            lastP[i] = (i < 64) ? 0.0f : tbv;   // lastP[t][b]: pred sums seeded with tb
        } else {
            out[u - NP - NW - 2 * NH - NL] = tbv;   // out seeded with tb; kCell atomicAdds
        }
    }
}

// ---------------- kEncStep: one encoder GRU step (192 blocks x 256) ----------------
// thread: b = lane, j = blk*4 + wave. h stored [k][b].
__global__ __launch_bounds__(256) void kEncStep(
    const float* __restrict__ x, const float* __restrict__ peT,
    const float* __restrict__ Wih, const float* __restrict__ Whh,
    const float* __restrict__ bih, const float* __restrict__ bhh,
    const float* __restrict__ hrd, float* __restrict__ hwr,
    __hip_bfloat16* __restrict__ encB, int t)
{
    __shared__ float lds_a[64 * 65];   // [b][k+pad]
    __shared__ float lds_h[64 * 64];   // [kk][b]
    const int tid = threadIdx.x;
    const int b   = tid & 63;
    const int jw  = __builtin_amdgcn_readfirstlane((int)(blockIdx.x * 4 + (tid >> 6)));

    const float* wir = Wih + (size_t)jw * D;
    const float* wiz = Wih + (size_t)(768 + jw) * D;
    const float* win = Wih + (size_t)(1536 + jw) * D;
    const float* whr = Whh + (size_t)jw * D;
    const float* whz = Whh + (size_t)(768 + jw) * D;
    const float* whn = Whh + (size_t)(1536 + jw) * D;

    float air = 0.f, aiz = 0.f, ain = 0.f, ahr = 0.f, ahz = 0.f, ahn = 0.f;
    for (int kc = 0; kc < D; kc += 64) {
        #pragma unroll
        for (int it = 0; it < 4; ++it) {
            const int idx = tid + 256 * it;
            const int row = idx >> 4, c4 = (idx & 15) * 4;
            const float4 xa = *(const float4*)(x + ((size_t)row * SEQ + t) * D + kc + c4);
            const float4 pe = *(const float4*)(peT + (size_t)t * D + kc + c4);
            const int la = row * 65 + c4;
            lds_a[la + 0] = xa.x + pe.x; lds_a[la + 1] = xa.y + pe.y;
            lds_a[la + 2] = xa.z + pe.z; lds_a[la + 3] = xa.w + pe.w;
        }
        const float4* gh = (const float4*)(hrd + kc * 64);
        float4* lh = (float4*)lds_h;
        #pragma unroll
        for (int it = 0; it < 4; ++it) lh[tid + 256 * it] = gh[tid + 256 * it];
        __syncthreads();
        #pragma unroll
        for (int kk = 0; kk < 64; kk += 4) {
            const float4 v0 = *(const float4*)(wir + kc + kk);
            const float4 v1 = *(const float4*)(wiz + kc + kk);
            const float4 v2 = *(const float4*)(win + kc + kk);
            const float4 v3 = *(const float4*)(whr + kc + kk);
            const float4 v4 = *(const float4*)(whz + kc + kk);
            const float4 v5 = *(const float4*)(whn + kc + kk);
            const float a0 = lds_a[b * 65 + kk + 0];
            const float a1 = lds_a[b * 65 + kk + 1];
            const float a2 = lds_a[b * 65 + kk + 2];
            const float a3 = lds_a[b * 65 + kk + 3];
            const float h0 = lds_h[(kk + 0) * 64 + b];
            const float h1 = lds_h[(kk + 1) * 64 + b];
            const float h2 = lds_h[(kk + 2) * 64 + b];
            const float h3 = lds_h[(kk + 3) * 64 + b];
            DOT4(air, v0, a0, a1, a2, a3);
            DOT4(aiz, v1, a0, a1, a2, a3);
            DOT4(ain, v2, a0, a1, a2, a3);
            DOT4(ahr, v3, h0, h1, h2, h3);
            DOT4(ahz, v4, h0, h1, h2, h3);
            DOT4(ahn, v5, h0, h1, h2, h3);
        }
        __syncthreads();
    }
    const float r = sigf(air + bih[jw] + ahr + bhh[jw]);
    const float z = sigf(aiz + bih[768 + jw] + ahz + bhh[768 + jw]);
    const float n = tanhfast(ain + bih[1536 + jw] + r * (ahn + bhh[1536 + jw]));
    const float ho = hrd[jw * 64 + b];
    const float hn = (1.f - z) * n + z * ho;
    hwr[jw * 64 + b] = hn;
    encB[((size_t)b * SEQ + t) * D + jw] = __float2bfloat16(hn);
}

// ---------------- kGemmMem: mem = enc @ mW^T + mb  (bf16 A, fp32 B, bf16 out) ----------------
__global__ __launch_bounds__(256) void kGemmMem(
    const __hip_bfloat16* __restrict__ encB, const float* __restrict__ mW,
    const float* __restrict__ mb, __hip_bfloat16* __restrict__ memB)
{
    __shared__ float As[16 * 64];
    __shared__ float Bs[16 * 64];
    const int tid = threadIdx.x;
    const int m0 = blockIdx.y * 64, n0 = blockIdx.x * 64;
    const int lr = tid >> 2;
    const int lk = (tid & 3) * 4;
    const int tm = (tid >> 4) * 4;
    const int tn = (tid & 15) * 4;

    float acc[4][4];
    #pragma unroll
    for (int i = 0; i < 4; ++i)
        #pragma unroll
        for (int j = 0; j < 4; ++j) acc[i][j] = 0.f;

    for (int kc = 0; kc < D; kc += 16) {
        const uint2 ua = *(const uint2*)(encB + (size_t)(m0 + lr) * D + kc + lk);
        float a0, a1, a2, a3;
        bf2x(ua.x, a0, a1); bf2x(ua.y, a2, a3);
        const float4 b4 = *(const float4*)(mW + (size_t)(n0 + lr) * D + kc + lk);
        As[(lk + 0) * 64 + lr] = a0; As[(lk + 1) * 64 + lr] = a1;
        As[(lk + 2) * 64 + lr] = a2; As[(lk + 3) * 64 + lr] = a3;
        Bs[(lk + 0) * 64 + lr] = b4.x; Bs[(lk + 1) * 64 + lr] = b4.y;
        Bs[(lk + 2) * 64 + lr] = b4.z; Bs[(lk + 3) * 64 + lr] = b4.w;
        __syncthreads();
        #pragma unroll
        for (int k = 0; k < 16; ++k) {
            const float4 av = *(const float4*)(As + k * 64 + tm);
            const float4 bv = *(const float4*)(Bs + k * 64 + tn);
            acc[0][0] = fmaf(av.x, bv.x, acc[0][0]); acc[0][1] = fmaf(av.x, bv.y, acc[0][1]);
            acc[0][2] = fmaf(av.x, bv.z, acc[0][2]); acc[0][3] = fmaf(av.x, bv.w, acc[0][3]);
            acc[1][0] = fmaf(av.y, bv.x, acc[1][0]); acc[1][1] = fmaf(av.y, bv.y, acc[1][1]);
            acc[1][2] = fmaf(av.y, bv.z, acc[1][2]); acc[1][3] = fmaf(av.y, bv.w, acc[1][3]);
            acc[2][0] = fmaf(av.z, bv.x, acc[2][0]); acc[2][1] = fmaf(av.z, bv.y, acc[2][1]);
            acc[2][2] = fmaf(av.z, bv.z, acc[2][2]); acc[2][3] = fmaf(av.z, bv.w, acc[2][3]);
            acc[3][0] = fmaf(av.w, bv.x, acc[3][0]); acc[3][1] = fmaf(av.w, bv.y, acc[3][1]);
            acc[3][2] = fmaf(av.w, bv.z, acc[3][2]); acc[3][3] = fmaf(av.w, bv.w, acc[3][3]);
        }
        __syncthreads();
    }
    const float bb0 = mb[n0 + tn + 0], bb1 = mb[n0 + tn + 1];
    const float bb2 = mb[n0 + tn + 2], bb3 = mb[n0 + tn + 3];
    #pragma unroll
    for (int i = 0; i < 4; ++i) {
        __hip_bfloat16* row = memB + (size_t)(m0 + tm + i) * D + n0 + tn;
        row[0] = __float2bfloat16(acc[i][0] + bb0);
        row[1] = __float2bfloat16(acc[i][1] + bb1);
        row[2] = __float2bfloat16(acc[i][2] + bb2);
        row[3] = __float2bfloat16(acc[i][3] + bb3);
    }
}

// ---------------- kQ: q[b][j] = h_t . qW[j] + qb[j]  (192 blocks x 256) ----------------
__global__ __launch_bounds__(256) void kQ(
    const float* __restrict__ qW, const float* __restrict__ qb,
    const float* __restrict__ hrd, float* __restrict__ qT)
{
    __shared__ float lds_h[64 * 64];
    const int tid = threadIdx.x;
    const int b   = tid & 63;
    const int jw  = __builtin_amdgcn_readfirstlane((int)(blockIdx.x * 4 + (tid >> 6)));
    const float* w = qW + (size_t)jw * D;
    float acc = 0.f;
    for (int kc = 0; kc < D; kc += 64) {
        const float4* gh = (const float4*)(hrd + kc * 64);
        float4* lh = (float4*)lds_h;
        #pragma unroll
        for (int it = 0; it < 4; ++it) lh[tid + 256 * it] = gh[tid + 256 * it];
        __syncthreads();
        #pragma unroll
        for (int kk = 0; kk < 64; kk += 4) {
            const float4 w4 = *(const float4*)(w + kc + kk);
            acc = fmaf(w4.x, lds_h[(kk + 0) * 64 + b], acc);
            acc = fmaf(w4.y, lds_h[(kk + 1) * 64 + b], acc);
            acc = fmaf(w4.z, lds_h[(kk + 2) * 64 + b], acc);
            acc = fmaf(w4.w, lds_h[(kk + 3) * 64 + b], acc);
        }
        __syncthreads();
    }
    qT[(size_t)b * D + jw] = acc + qb[jw];
}

// ---------------- kAttn: tanh-attention, unnormalized ctx partials ----------------
// grid 256 = (b = blk&63, ch = blk>>6), block 512 (8 waves), 75 s-rows per block
__global__ __launch_bounds__(512) void kAttn(
    const float* __restrict__ qT, const __hip_bfloat16* __restrict__ memB,
    const __hip_bfloat16* __restrict__ encB, const float* __restrict__ pW,
    const float* __restrict__ pb, float* __restrict__ ctxP, float* __restrict__ seP)
{
    __shared__ float s_q[768];
    __shared__ float s_pw[768];
    __shared__ float s_cx[768];
    __shared__ float s_se[1];
    const int tid = threadIdx.x;
    const int b  = blockIdx.x & 63;
    const int ch = blockIdx.x >> 6;
    for (int i = tid; i < 768; i += 512) {
        s_q[i]  = qT[(size_t)b * D + i];
        s_pw[i] = pW[i];
        s_cx[i] = 0.f;
    }
    if (tid == 0) s_se[0] = 0.f;
    __syncthreads();
    const int lane = tid & 63;
    const int wv   = tid >> 6;
    float cacc[12];
    #pragma unroll
    for (int i = 0; i < 12; ++i) cacc[i] = 0.f;
    float seacc = 0.f;
    const float pbv = pb[0];
    const int s0 = ch * 75;
    for (int s = s0 + wv; s < s0 + 75; s += 8) {
        const __hip_bfloat16* mrow = memB + ((size_t)b * SEQ + s) * D;
        const __hip_bfloat16* erow = encB + ((size_t)b * SEQ + s) * D;
        float lp = 0.f;
        #pragma unroll
        for (int g = 0; g < 3; ++g) {
            const int d0 = g * 256 + lane * 4;
            const uint2 mu = *(const uint2*)(mrow + d0);
            float m0, m1, m2, m3;
            bf2x(mu.x, m0, m1); bf2x(mu.y, m2, m3);
            const float4 qv = *(const float4*)(s_q + d0);
            const float4 pv = *(const float4*)(s_pw + d0);
            lp = fmaf(pv.x, tanhfast(m0 + qv.x), lp);
            lp = fmaf(pv.y, tanhfast(m1 + qv.y), lp);
            lp = fmaf(pv.z, tanhfast(m2 + qv.z), lp);
            lp = fmaf(pv.w, tanhfast(m3 + qv.w), lp);
        }
        #pragma unroll
        for (int o = 32; o > 0; o >>= 1) lp += __shfl_xor(lp, o, 64);
        const float e = __expf(lp + pbv);    // identical on all 64 lanes
        seacc += e;
        #pragma unroll
        for (int g = 0; g < 3; ++g) {
            const int d0 = g * 256 + lane * 4;
            const uint2 eu = *(const uint2*)(erow + d0);
            float e0, e1, e2, e3;
            bf2x(eu.x, e0, e1); bf2x(eu.y, e2, e3);
            cacc[g * 4 + 0] = fmaf(e, e0, cacc[g * 4 + 0]);
            cacc[g * 4 + 1] = fmaf(e, e1, cacc[g * 4 + 1]);
            cacc[g * 4 + 2] = fmaf(e, e2, cacc[g * 4 + 2]);
            cacc[g * 4 + 3] = fmaf(e, e3, cacc[g * 4 + 3]);
        }
    }
    #pragma unroll
    for (int g = 0; g < 3; ++g) {
        const int d0 = g * 256 + lane * 4;
        atomicAdd(&s_cx[d0 + 0], cacc[g * 4 + 0]);
        atomicAdd(&s_cx[d0 + 1], cacc[g * 4 + 1]);
        atomicAdd(&s_cx[d0 + 2], cacc[g * 4 + 2]);
        atomicAdd(&s_cx[d0 + 3], cacc[g * 4 + 3]);
    }
    if (lane == 0) atomicAdd(&s_se[0], seacc);
    __syncthreads();
    float* cp = ctxP + ((size_t)ch * 64 + b) * D;
    for (int i = tid; i < 768; i += 512) cp[i] = s_cx[i];
    if (tid == 0) seP[ch * 64 + b] = s_se[0];
}

// ---------------- kCell: decoder GRU cell + pred (192 blocks x 256) ----------------
__global__ __launch_bounds__(256) void kCell(
    const float* __restrict__ Wc, const float* __restrict__ W0,
    const float* __restrict__ dWhh, const float* __restrict__ dbih,
    const float* __restrict__ dbhh, const float* __restrict__ tW,
    const float* __restrict__ ctxP, const float* __restrict__ seP,
    const float* __restrict__ lastT, float* __restrict__ lastN,
    const float* __restrict__ hrd, float* __restrict__ hwr,
    float* __restrict__ out, int t)
{
    __shared__ float lds_h[64 * 64];   // [kk][b]
    __shared__ float lds_c[64 * 65];   // [b][kk+pad]
    const int tid = threadIdx.x;
    const int b   = tid & 63;
    const int jw  = __builtin_amdgcn_readfirstlane((int)(blockIdx.x * 4 + (tid >> 6)));
    const float* whr = dWhh + (size_t)jw * D;
    const float* whz = dWhh + (size_t)(768 + jw) * D;
    const float* whn = dWhh + (size_t)(1536 + jw) * D;
    const float* wcr = Wc + (size_t)jw * D;
    const float* wcz = Wc + (size_t)(768 + jw) * D;
    const float* wcn = Wc + (size_t)(1536 + jw) * D;
    float cir = 0.f, ciz = 0.f, cin_ = 0.f, ahr = 0.f, ahz = 0.f, ahn = 0.f;
    for (int kc = 0; kc < D; kc += 64) {
        const float4* gh = (const float4*)(hrd + kc * 64);
        float4* lh = (float4*)lds_h;
        #pragma unroll
        for (int it = 0; it < 4; ++it) lh[tid + 256 * it] = gh[tid + 256 * it];
        #pragma unroll
        for (int it = 0; it < 4; ++it) {
            const int idx = tid + 256 * it;
            const int row = idx >> 4, c4 = (idx & 15) * 4;
            const float* p0 = ctxP + (size_t)row * D + kc + c4;
            const float4 u0 = *(const float4*)(p0);
            const float4 u1 = *(const float4*)(p0 + 64 * D);
            const float4 u2 = *(const float4*)(p0 + 2 * 64 * D);
            const float4 u3 = *(const float4*)(p0 + 3 * 64 * D);
            const int la = row * 65 + c4;
            lds_c[la + 0] = u0.x + u1.x + u2.x + u3.x;
            lds_c[la + 1] = u0.y + u1.y + u2.y + u3.y;
            lds_c[la + 2] = u0.z + u1.z + u2.z + u3.z;
            lds_c[la + 3] = u0.w + u1.w + u2.w + u3.w;
        }
        __syncthreads();
        #pragma unroll
        for (int kk = 0; kk < 64; kk += 4) {
            const float4 v0 = *(const float4*)(wcr + kc + kk);
            const float4 v1 = *(const float4*)(wcz + kc + kk);
            const float4 v2 = *(const float4*)(wcn + kc + kk);
            const float4 v3 = *(const float4*)(whr + kc + kk);
            const float4 v4 = *(const float4*)(whz + kc + kk);
            const float4 v5 = *(const float4*)(whn + kc + kk);
            const float c0 = lds_c[b * 65 + kk + 0];
            const float c1 = lds_c[b * 65 + kk + 1];
            const float c2 = lds_c[b * 65 + kk + 2];
            const float c3 = lds_c[b * 65 + kk + 3];
            const float h0 = lds_h[(kk + 0) * 64 + b];
            const float h1 = lds_h[(kk + 1) * 64 + b];
            const float h2 = lds_h[(kk + 2) * 64 + b];
            const float h3 = lds_h[(kk + 3) * 64 + b];
            DOT4(cir, v0, c0, c1, c2, c3);
            DOT4(ciz, v1, c0, c1, c2, c3);
            DOT4(cin_, v2, c0, c1, c2, c3);
            DOT4(ahr, v3, h0, h1, h2, h3);
            DOT4(ahz, v4, h0, h1, h2, h3);
            DOT4(ahn, v5, h0, h1, h2, h3);
        }
        __syncthreads();
    }
    const float se = seP[b] + seP[64 + b] + seP[128 + b] + seP[192 + b];
    const float inv = 1.f / se;
    const float lst = lastT[b];
    const float gir = cir * inv + W0[jw] * lst + dbih[jw];
    const float giz = ciz * inv + W0[768 + jw] * lst + dbih[768 + jw];
    const float gin = cin_ * inv + W0[1536 + jw] * lst + dbih[1536 + jw];
    const float r = sigf(gir + ahr + dbhh[jw]);
    const float z = sigf(giz + ahz + dbhh[768 + jw]);
    const float n = tanhfast(gin + r * (ahn + dbhh[1536 + jw]));
    const float ho = hrd[jw * 64 + b];
    const float hn = (1.f - z) * n + z * ho;
    hwr[jw * 64 + b] = hn;

    // pred partial: out[b][t] += sum_j tW[j] * hn[j][b]  (out pre-seeded with tb)
    __syncthreads();
    lds_h[(tid >> 6) * 64 + b] = tW[jw] * hn;
    __syncthreads();
    if (tid < 64) {
        const float p = lds_h[tid] + lds_h[64 + tid] + lds_h[128 + tid] + lds_h[192 + tid];
        atomicAdd(&out[(size_t)tid * TDEC + t], p);
        atomicAdd(&lastN[tid], p);
    }
}

// ---------------- launch ----------------
extern "C" void kernel_launch(void* const* d_in, const int* in_sizes, int n_in,
                              void* d_out, int out_size, void* d_ws, size_t ws_size,
                              hipStream_t stream) {
    const float* x    = (const float*)d_in[0];
    const float* eWih = (const float*)d_in[1];
    const float* eWhh = (const float*)d_in[2];
    const float* ebih = (const float*)d_in[3];
    const float* ebhh = (const float*)d_in[4];
    const float* dWih = (const float*)d_in[5];
    const float* dWhh = (const float*)d_in[6];
    const float* dbih = (const float*)d_in[7];
    const float* dbhh = (const float*)d_in[8];
    const float* qW   = (const float*)d_in[9];
    const float* qb   = (const float*)d_in[10];
    const float* mW   = (const float*)d_in[11];
    const float* mb   = (const float*)d_in[12];
    const float* pW   = (const float*)d_in[13];
    const float* pb   = (const float*)d_in[14];
    const float* tW   = (const float*)d_in[15];
    const float* tb   = (const float*)d_in[16];
    float* out = (float*)d_out;

    char* w = (char*)d_ws;
    auto alloc = [&](size_t bytes) -> char* {
        char* p = w; w += (bytes + 255) & ~(size_t)255; return p;
    };
    // total ~69 MB
    float* peT   = (float*)alloc((size_t)SEQ * D * 4);
    float* Wc    = (float*)alloc((size_t)G3 * D * 4);
    float* W0    = (float*)alloc((size_t)G3 * 4);
    __hip_bfloat16* encB = (__hip_bfloat16*)alloc((size_t)BS * SEQ * D * 2);
    __hip_bfloat16* memB = (__hip_bfloat16*)alloc((size_t)BS * SEQ * D * 2);
    float* hE0   = (float*)alloc((size_t)D * 64 * 4);
    float* hE1   = (float*)alloc((size_t)D * 64 * 4);
    float* hD0   = (float*)alloc((size_t)D * 64 * 4);
    float* hD1   = (float*)alloc((size_t)D * 64 * 4);
    float* qT    = (float*)alloc((size_t)BS * D * 4);
    float* ctxP  = (float*)alloc((size_t)4 * 64 * D * 4);
    float* seP   = (float*)alloc(4 * 64 * 4);
    float* lastP = (float*)alloc(101 * 64 * 4);

    kPrep<<<512, 256, 0, stream>>>(dWih, tb, peT, Wc, W0, hE0, hD0, lastP, out);

    for (int t = 0; t < SEQ; ++t) {
        const float* hr = (t & 1) ? hE1 : hE0;
        float*       hw = (t & 1) ? hE0 : hE1;
        kEncStep<<<192, 256, 0, stream>>>(x, peT, eWih, eWhh, ebih, ebhh, hr, hw, encB, t);
    }

    kGemmMem<<<dim3(12, 300), 256, 0, stream>>>(encB, mW, mb, memB);

    for (int t = 0; t < TDEC; ++t) {
        const float* hr = (t & 1) ? hD1 : hD0;
        float*       hw = (t & 1) ? hD0 : hD1;
        kQ<<<192, 256, 0, stream>>>(qW, qb, hr, qT);
        kAttn<<<256, 512, 0, stream>>>(qT, memB, encB, pW, pb, ctxP, seP);
        kCell<<<192, 256, 0, stream>>>(Wc, W0, dWhh, dbih, dbhh, tW, ctxP, seP,
                                       lastP + t * 64, lastP + (t + 1) * 64,
                                       hr, hw, out, t);
    }
}

// Round 4
// 25573.422 us; speedup vs baseline: 2.2957x; 1.3523x over previous
//
#include <hip/hip_runtime.h>
#include <hip/hip_bf16.h>
#include <cstdint>
#include <cstddef>

#define D    768
#define G3   2304
#define BS   64
#define SEQ  300
#define TDEC 100
#define TCH  25          // encoder gi chunk length (12 chunks of 25)

typedef unsigned int u32;

__device__ __forceinline__ float sigf(float x) { return 1.0f / (1.0f + __expf(-x)); }
__device__ __forceinline__ float tanhfast(float x) {
    float e = __expf(2.0f * x);
    return 1.0f - 2.0f / (e + 1.0f);
}
__device__ __forceinline__ void bf2x(u32 u, float& a, float& b) {
    union { u32 i; float f; } xx, yy;
    xx.i = u << 16; yy.i = u & 0xffff0000u; a = xx.f; b = yy.f;
}
__device__ __forceinline__ float bf1(__hip_bfloat16 h) { return __bfloat162float(h); }

#define DOT4(acc, wv, x0, x1, x2, x3) \
    acc = fmaf((wv).x,(x0), fmaf((wv).y,(x1), fmaf((wv).z,(x2), fmaf((wv).w,(x3),(acc)))))

// ---------------- kPrep: dec_Wih split, init h/last/out ----------------
__global__ __launch_bounds__(256) void kPrep(
    const float* __restrict__ decWih, const float* __restrict__ tb,
    float* __restrict__ Wc, float* __restrict__ W0,
    float* __restrict__ hE0, float* __restrict__ hD0,
    float* __restrict__ lastP, float* __restrict__ out)
{
    const int NW = G3 * 769;         // 1771776
    const int NH = D * 64;           // 49152
    const int NL = (TDEC + 1) * 64;
    const int NO = 64 * TDEC;
    const int TOT = NW + 2 * NH + NL + NO;
    const float tbv = tb[0];
    const int stride = gridDim.x * blockDim.x;
    for (int u = blockIdx.x * blockDim.x + threadIdx.x; u < TOT; u += stride) {
        if (u < NW) {
            int g = u / 769; int c = u % 769;
            float w = decWih[u];
            if (c == 0) W0[g] = w; else Wc[(size_t)g * D + (c - 1)] = w;
        } else if (u < NW + NH) {
            hE0[u - NW] = 0.0f;
        } else if (u < NW + 2 * NH) {
            hD0[u - NW - NH] = 0.0f;
        } else if (u < NW + 2 * NH + NL) {
            int i = u - NW - 2 * NH;
            lastP[i] = (i < 64) ? 0.0f : tbv;   // lastP[t][b]: pred sums seeded with tb
        } else {
            out[u - NW - 2 * NH - NL] = tbv;    // out seeded with tb; kCell atomicAdds
        }
    }
}

// ---------------- kGi: gi[t][gj][b] = (x[b,t,:]+pe[t,:]) . Wih[gj,:]  (bf16 out) ----------------
// grid (36 gj-tiles, TCH t's), block 256, 64x64 tile, K-chunk 16
__global__ __launch_bounds__(256) void kGi(
    const float* __restrict__ x, const float* __restrict__ Wih,
    __hip_bfloat16* __restrict__ giB, int t0)
{
    __shared__ float As[16 * 64];
    __shared__ float Bs[16 * 64];
    const int tid = threadIdx.x;
    const int m0 = blockIdx.x * 64;       // gj tile base
    const int tc = blockIdx.y;
    const int t  = t0 + tc;
    const int lr = tid >> 2;
    const int lk = (tid & 3) * 4;
    const int tm = (tid >> 4) * 4;
    const int tn = (tid & 15) * 4;
    const float tf = (float)t;

    float acc[4][4];
    #pragma unroll
    for (int i = 0; i < 4; ++i)
        #pragma unroll
        for (int j = 0; j < 4; ++j) acc[i][j] = 0.f;

    for (int kc = 0; kc < D; kc += 16) {
        const float4 a4 = *(const float4*)(Wih + (size_t)(m0 + lr) * D + kc + lk);
        float4 b4 = *(const float4*)(x + ((size_t)lr * SEQ + t) * D + kc + lk);
        // PE inline: k0 = kc+lk (even); pe[even]=sin(t*dv), pe[odd]=cos(t*dv), dv=exp(-0.02398526*i)
        const int i0 = (kc + lk) >> 1;
        const float dv0 = __expf(-0.0239852614f * (float)i0);
        const float dv1 = __expf(-0.0239852614f * (float)(i0 + 1));
        float s0, c0, s1, c1;
        __sincosf(tf * dv0, &s0, &c0);
        __sincosf(tf * dv1, &s1, &c1);
        b4.x += s0; b4.y += c0; b4.z += s1; b4.w += c1;
        As[(lk + 0) * 64 + lr] = a4.x; As[(lk + 1) * 64 + lr] = a4.y;
        As[(lk + 2) * 64 + lr] = a4.z; As[(lk + 3) * 64 + lr] = a4.w;
        Bs[(lk + 0) * 64 + lr] = b4.x; Bs[(lk + 1) * 64 + lr] = b4.y;
        Bs[(lk + 2) * 64 + lr] = b4.z; Bs[(lk + 3) * 64 + lr] = b4.w;
        __syncthreads();
        #pragma unroll
        for (int k = 0; k < 16; ++k) {
            const float4 av = *(const float4*)(As + k * 64 + tm);
            const float4 bv = *(const float4*)(Bs + k * 64 + tn);
            acc[0][0] = fmaf(av.x, bv.x, acc[0][0]); acc[0][1] = fmaf(av.x, bv.y, acc[0][1]);
            acc[0][2] = fmaf(av.x, bv.z, acc[0][2]); acc[0][3] = fmaf(av.x, bv.w, acc[0][3]);
            acc[1][0] = fmaf(av.y, bv.x, acc[1][0]); acc[1][1] = fmaf(av.y, bv.y, acc[1][1]);
            acc[1][2] = fmaf(av.y, bv.z, acc[1][2]); acc[1][3] = fmaf(av.y, bv.w, acc[1][3]);
            acc[2][0] = fmaf(av.z, bv.x, acc[2][0]); acc[2][1] = fmaf(av.z, bv.y, acc[2][1]);
            acc[2][2] = fmaf(av.z, bv.z, acc[2][2]); acc[2][3] = fmaf(av.z, bv.w, acc[2][3]);
            acc[3][0] = fmaf(av.w, bv.x, acc[3][0]); acc[3][1] = fmaf(av.w, bv.y, acc[3][1]);
            acc[3][2] = fmaf(av.w, bv.z, acc[3][2]); acc[3][3] = fmaf(av.w, bv.w, acc[3][3]);
        }
        __syncthreads();
    }
    // store: giB[(tc*G3 + gj)*64 + b]
    #pragma unroll
    for (int i = 0; i < 4; ++i) {
        __hip_bfloat16* row = giB + ((size_t)tc * G3 + m0 + tm + i) * 64 + tn;
        row[0] = __float2bfloat16(acc[i][0]);
        row[1] = __float2bfloat16(acc[i][1]);
        row[2] = __float2bfloat16(acc[i][2]);
        row[3] = __float2bfloat16(acc[i][3]);
    }
}

// ---------------- kEncStep2: h-recurrence only (192 blocks x 256) ----------------
__global__ __launch_bounds__(256) void kEncStep2(
    const __hip_bfloat16* __restrict__ giT,   // pre-offset [3*768][64] for this t
    const float* __restrict__ Whh,
    const float* __restrict__ bih, const float* __restrict__ bhh,
    const float* __restrict__ hrd, float* __restrict__ hwr,
    __hip_bfloat16* __restrict__ encB, int t)
{
    __shared__ float lds_h[64 * 64];   // [kk][b]
    const int tid = threadIdx.x;
    const int b   = tid & 63;
    const int jw  = __builtin_amdgcn_readfirstlane((int)(blockIdx.x * 4 + (tid >> 6)));

    const float* whr = Whh + (size_t)jw * D;
    const float* whz = Whh + (size_t)(768 + jw) * D;
    const float* whn = Whh + (size_t)(1536 + jw) * D;

    float ahr = 0.f, ahz = 0.f, ahn = 0.f;
    for (int kc = 0; kc < D; kc += 64) {
        const float4* gh = (const float4*)(hrd + kc * 64);
        float4* lh = (float4*)lds_h;
        #pragma unroll
        for (int it = 0; it < 4; ++it) lh[tid + 256 * it] = gh[tid + 256 * it];
        __syncthreads();
        #pragma unroll
        for (int kk = 0; kk < 64; kk += 4) {
            const float4 v3 = *(const float4*)(whr + kc + kk);
            const float4 v4 = *(const float4*)(whz + kc + kk);
            const float4 v5 = *(const float4*)(whn + kc + kk);
            const float h0 = lds_h[(kk + 0) * 64 + b];
            const float h1 = lds_h[(kk + 1) * 64 + b];
            const float h2 = lds_h[(kk + 2) * 64 + b];
            const float h3 = lds_h[(kk + 3) * 64 + b];
            DOT4(ahr, v3, h0, h1, h2, h3);
            DOT4(ahz, v4, h0, h1, h2, h3);
            DOT4(ahn, v5, h0, h1, h2, h3);
        }
        __syncthreads();
    }
    const float gir = bf1(giT[(size_t)jw * 64 + b]);
    const float giz = bf1(giT[(size_t)(768 + jw) * 64 + b]);
    const float gin = bf1(giT[(size_t)(1536 + jw) * 64 + b]);
    const float r = sigf(gir + bih[jw] + ahr + bhh[jw]);
    const float z = sigf(giz + bih[768 + jw] + ahz + bhh[768 + jw]);
    const float n = tanhfast(gin + bih[1536 + jw] + r * (ahn + bhh[1536 + jw]));
    const float ho = hrd[jw * 64 + b];
    const float hn = (1.f - z) * n + z * ho;
    hwr[jw * 64 + b] = hn;
    encB[((size_t)b * SEQ + t) * D + jw] = __float2bfloat16(hn);
}

// ---------------- kGemmMem: mem = enc @ mW^T + mb  (bf16 A, fp32 B, bf16 out) ----------------
__global__ __launch_bounds__(256) void kGemmMem(
    const __hip_bfloat16* __restrict__ encB, const float* __restrict__ mW,
    const float* __restrict__ mb, __hip_bfloat16* __restrict__ memB)
{
    __shared__ float As[16 * 64];
    __shared__ float Bs[16 * 64];
    const int tid = threadIdx.x;
    const int m0 = blockIdx.y * 64, n0 = blockIdx.x * 64;
    const int lr = tid >> 2;
    const int lk = (tid & 3) * 4;
    const int tm = (tid >> 4) * 4;
    const int tn = (tid & 15) * 4;

    float acc[4][4];
    #pragma unroll
    for (int i = 0; i < 4; ++i)
        #pragma unroll
        for (int j = 0; j < 4; ++j) acc[i][j] = 0.f;

    for (int kc = 0; kc < D; kc += 16) {
        const uint2 ua = *(const uint2*)(encB + (size_t)(m0 + lr) * D + kc + lk);
        float a0, a1, a2, a3;
        bf2x(ua.x, a0, a1); bf2x(ua.y, a2, a3);
        const float4 b4 = *(const float4*)(mW + (size_t)(n0 + lr) * D + kc + lk);
        As[(lk + 0) * 64 + lr] = a0; As[(lk + 1) * 64 + lr] = a1;
        As[(lk + 2) * 64 + lr] = a2; As[(lk + 3) * 64 + lr] = a3;
        Bs[(lk + 0) * 64 + lr] = b4.x; Bs[(lk + 1) * 64 + lr] = b4.y;
        Bs[(lk + 2) * 64 + lr] = b4.z; Bs[(lk + 3) * 64 + lr] = b4.w;
        __syncthreads();
        #pragma unroll
        for (int k = 0; k < 16; ++k) {
            const float4 av = *(const float4*)(As + k * 64 + tm);
            const float4 bv = *(const float4*)(Bs + k * 64 + tn);
            acc[0][0] = fmaf(av.x, bv.x, acc[0][0]); acc[0][1] = fmaf(av.x, bv.y, acc[0][1]);
            acc[0][2] = fmaf(av.x, bv.z, acc[0][2]); acc[0][3] = fmaf(av.x, bv.w, acc[0][3]);
            acc[1][0] = fmaf(av.y, bv.x, acc[1][0]); acc[1][1] = fmaf(av.y, bv.y, acc[1][1]);
            acc[1][2] = fmaf(av.y, bv.z, acc[1][2]); acc[1][3] = fmaf(av.y, bv.w, acc[1][3]);
            acc[2][0] = fmaf(av.z, bv.x, acc[2][0]); acc[2][1] = fmaf(av.z, bv.y, acc[2][1]);
            acc[2][2] = fmaf(av.z, bv.z, acc[2][2]); acc[2][3] = fmaf(av.z, bv.w, acc[2][3]);
            acc[3][0] = fmaf(av.w, bv.x, acc[3][0]); acc[3][1] = fmaf(av.w, bv.y, acc[3][1]);
            acc[3][2] = fmaf(av.w, bv.z, acc[3][2]); acc[3][3] = fmaf(av.w, bv.w, acc[3][3]);
        }
        __syncthreads();
    }
    const float bb0 = mb[n0 + tn + 0], bb1 = mb[n0 + tn + 1];
    const float bb2 = mb[n0 + tn + 2], bb3 = mb[n0 + tn + 3];
    #pragma unroll
    for (int i = 0; i < 4; ++i) {
        __hip_bfloat16* row = memB + (size_t)(m0 + tm + i) * D + n0 + tn;
        row[0] = __float2bfloat16(acc[i][0] + bb0);
        row[1] = __float2bfloat16(acc[i][1] + bb1);
        row[2] = __float2bfloat16(acc[i][2] + bb2);
        row[3] = __float2bfloat16(acc[i][3] + bb3);
    }
}

// ---------------- kQ: q[b][j] = h_t . qW[j] + qb[j]  (192 blocks x 256) ----------------
__global__ __launch_bounds__(256) void kQ(
    const float* __restrict__ qW, const float* __restrict__ qb,
    const float* __restrict__ hrd, float* __restrict__ qT)
{
    __shared__ float lds_h[64 * 64];
    const int tid = threadIdx.x;
    const int b   = tid & 63;
    const int jw  = __builtin_amdgcn_readfirstlane((int)(blockIdx.x * 4 + (tid >> 6)));
    const float* w = qW + (size_t)jw * D;
    float acc = 0.f;
    for (int kc = 0; kc < D; kc += 64) {
        const float4* gh = (const float4*)(hrd + kc * 64);
        float4* lh = (float4*)lds_h;
        #pragma unroll
        for (int it = 0; it < 4; ++it) lh[tid + 256 * it] = gh[tid + 256 * it];
        __syncthreads();
        #pragma unroll
        for (int kk = 0; kk < 64; kk += 4) {
            const float4 w4 = *(const float4*)(w + kc + kk);
            acc = fmaf(w4.x, lds_h[(kk + 0) * 64 + b], acc);
            acc = fmaf(w4.y, lds_h[(kk + 1) * 64 + b], acc);
            acc = fmaf(w4.z, lds_h[(kk + 2) * 64 + b], acc);
            acc = fmaf(w4.w, lds_h[(kk + 3) * 64 + b], acc);
        }
        __syncthreads();
    }
    qT[(size_t)b * D + jw] = acc + qb[jw];
}

// ---------------- kAttn: tanh-attention, 2 ctx partials in [k][b] layout ----------------
// grid 128 = (b = blk&63, ch = blk>>6 in {0,1}), block 1024 (16 waves), 150 rows/block
__global__ __launch_bounds__(1024) void kAttn(
    const float* __restrict__ qT, const __hip_bfloat16* __restrict__ memB,
    const __hip_bfloat16* __restrict__ encB, const float* __restrict__ pW,
    const float* __restrict__ pb, float* __restrict__ ctxP, float* __restrict__ seP)
{
    __shared__ float s_q[768];
    __shared__ float s_pw[768];
    __shared__ float s_cx[768];
    __shared__ float s_se[1];
    const int tid = threadIdx.x;
    const int b  = blockIdx.x & 63;
    const int ch = blockIdx.x >> 6;
    for (int i = tid; i < 768; i += 1024) {
        s_q[i]  = qT[(size_t)b * D + i];
        s_pw[i] = pW[i];
        s_cx[i] = 0.f;
    }
    if (tid == 0) s_se[0] = 0.f;
    __syncthreads();
    const int lane = tid & 63;
    const int wv   = tid >> 6;
    float cacc[12];
    #pragma unroll
    for (int i = 0; i < 12; ++i) cacc[i] = 0.f;
    float seacc = 0.f;
    const float pbv = pb[0];
    const int s0 = ch * 150;
    for (int s = s0 + wv; s < s0 + 150; s += 16) {
        const __hip_bfloat16* mrow = memB + ((size_t)b * SEQ + s) * D;
        const __hip_bfloat16* erow = encB + ((size_t)b * SEQ + s) * D;
        float lp = 0.f;
        #pragma unroll
        for (int g = 0; g < 3; ++g) {
            const int d0 = g * 256 + lane * 4;
            const uint2 mu = *(const uint2*)(mrow + d0);
            float m0, m1, m2, m3;
            bf2x(mu.x, m0, m1); bf2x(mu.y, m2, m3);
            const float4 qv = *(const float4*)(s_q + d0);
            const float4 pv = *(const float4*)(s_pw + d0);
            lp = fmaf(pv.x, tanhfast(m0 + qv.x), lp);
            lp = fmaf(pv.y, tanhfast(m1 + qv.y), lp);
            lp = fmaf(pv.z, tanhfast(m2 + qv.z), lp);
            lp = fmaf(pv.w, tanhfast(m3 + qv.w), lp);
        }
        #pragma unroll
        for (int o = 32; o > 0; o >>= 1) lp += __shfl_xor(lp, o, 64);
        const float e = __expf(lp + pbv);    // identical on all 64 lanes
        seacc += e;
        #pragma unroll
        for (int g = 0; g < 3; ++g) {
            const int d0 = g * 256 + lane * 4;
            const uint2 eu = *(const uint2*)(erow + d0);
            float e0, e1, e2, e3;
            bf2x(eu.x, e0, e1); bf2x(eu.y, e2, e3);
            cacc[g * 4 + 0] = fmaf(e, e0, cacc[g * 4 + 0]);
            cacc[g * 4 + 1] = fmaf(e, e1, cacc[g * 4 + 1]);
            cacc[g * 4 + 2] = fmaf(e, e2, cacc[g * 4 + 2]);
            cacc[g * 4 + 3] = fmaf(e, e3, cacc[g * 4 + 3]);
        }
    }
    #pragma unroll
    for (int g = 0; g < 3; ++g) {
        const int d0 = g * 256 + lane * 4;
        atomicAdd(&s_cx[d0 + 0], cacc[g * 4 + 0]);
        atomicAdd(&s_cx[d0 + 1], cacc[g * 4 + 1]);
        atomicAdd(&s_cx[d0 + 2], cacc[g * 4 + 2]);
        atomicAdd(&s_cx[d0 + 3], cacc[g * 4 + 3]);
    }
    if (lane == 0) atomicAdd(&s_se[0], seacc);
    __syncthreads();
    // write partial ctx transposed: ctxP[(ch*768 + k)*64 + b]
    for (int i = tid; i < 768; i += 1024) ctxP[((size_t)ch * 768 + i) * 64 + b] = s_cx[i];
    if (tid == 0) seP[ch * 64 + b] = s_se[0];
}

// ---------------- kCell: decoder GRU cell + pred (192 blocks x 256) ----------------
__global__ __launch_bounds__(256) void kCell(
    const float* __restrict__ Wc, const float* __restrict__ W0,
    const float* __restrict__ dWhh, const float* __restrict__ dbih,
    const float* __restrict__ dbhh, const float* __restrict__ tW,
    const float* __restrict__ ctxP, const float* __restrict__ seP,
    const float* __restrict__ lastT, float* __restrict__ lastN,
    const float* __restrict__ hrd, float* __restrict__ hwr,
    float* __restrict__ out, int t)
{
    __shared__ float lds_h[64 * 64];   // [kk][b]
    __shared__ float lds_c[64 * 64];   // [kk][b]
    const int tid = threadIdx.x;
    const int b   = tid & 63;
    const int jw  = __builtin_amdgcn_readfirstlane((int)(blockIdx.x * 4 + (tid >> 6)));
    const float* whr = dWhh + (size_t)jw * D;
    const float* whz = dWhh + (size_t)(768 + jw) * D;
    const float* whn = dWhh + (size_t)(1536 + jw) * D;
    const float* wcr = Wc + (size_t)jw * D;
    const float* wcz = Wc + (size_t)(768 + jw) * D;
    const float* wcn = Wc + (size_t)(1536 + jw) * D;
    float cir = 0.f, ciz = 0.f, cin_ = 0.f, ahr = 0.f, ahz = 0.f, ahn = 0.f;
    for (int kc = 0; kc < D; kc += 64) {
        const float4* gh = (const float4*)(hrd + kc * 64);
        const float4* g0 = (const float4*)(ctxP + (size_t)kc * 64);
        const float4* g1 = (const float4*)(ctxP + (size_t)(768 + kc) * 64);
        float4* lh = (float4*)lds_h;
        float4* lc = (float4*)lds_c;
        #pragma unroll
        for (int it = 0; it < 4; ++it) {
            lh[tid + 256 * it] = gh[tid + 256 * it];
            const float4 u0 = g0[tid + 256 * it];
            const float4 u1 = g1[tid + 256 * it];
            float4 s; s.x = u0.x + u1.x; s.y = u0.y + u1.y; s.z = u0.z + u1.z; s.w = u0.w + u1.w;
            lc[tid + 256 * it] = s;
        }
        __syncthreads();
        #pragma unroll
        for (int kk = 0; kk < 64; kk += 4) {
            const float4 v0 = *(const float4*)(wcr + kc + kk);
            const float4 v1 = *(const float4*)(wcz + kc + kk);
            const float4 v2 = *(const float4*)(wcn + kc + kk);
            const float4 v3 = *(const float4*)(whr + kc + kk);
            const float4 v4 = *(const float4*)(whz + kc + kk);
            const float4 v5 = *(const float4*)(whn + kc + kk);
            const float c0 = lds_c[(kk + 0) * 64 + b];
            const float c1 = lds_c[(kk + 1) * 64 + b];
            const float c2 = lds_c[(kk + 2) * 64 + b];
            const float c3 = lds_c[(kk + 3) * 64 + b];
            const float h0 = lds_h[(kk + 0) * 64 + b];
            const float h1 = lds_h[(kk + 1) * 64 + b];
            const float h2 = lds_h[(kk + 2) * 64 + b];
            const float h3 = lds_h[(kk + 3) * 64 + b];
            DOT4(cir, v0, c0, c1, c2, c3);
            DOT4(ciz, v1, c0, c1, c2, c3);
            DOT4(cin_, v2, c0, c1, c2, c3);
            DOT4(ahr, v3, h0, h1, h2, h3);
            DOT4(ahz, v4, h0, h1, h2, h3);
            DOT4(ahn, v5, h0, h1, h2, h3);
        }
        __syncthreads();
    }
    const float se = seP[b] + seP[64 + b];
    const float inv = 1.f / se;
    const float lst = lastT[b];
    const float gir = cir * inv + W0[jw] * lst + dbih[jw];
    const float giz = ciz * inv + W0[768 + jw] * lst + dbih[768 + jw];
    const float gin = cin_ * inv + W0[1536 + jw] * lst + dbih[1536 + jw];
    const float r = sigf(gir + ahr + dbhh[jw]);
    const float z = sigf(giz + ahz + dbhh[768 + jw]);
    const float n = tanhfast(gin + r * (ahn + dbhh[1536 + jw]));
    const float ho = hrd[jw * 64 + b];
    const float hn = (1.f - z) * n + z * ho;
    hwr[jw * 64 + b] = hn;

    // pred partial: out[b][t] += sum_j tW[j] * hn[j][b]  (out pre-seeded with tb)
    __syncthreads();
    lds_h[(tid >> 6) * 64 + b] = tW[jw] * hn;
    __syncthreads();
    if (tid < 64) {
        const float p = lds_h[tid] + lds_h[64 + tid] + lds_h[128 + tid] + lds_h[192 + tid];
        atomicAdd(&out[(size_t)tid * TDEC + t], p);
        atomicAdd(&lastN[tid], p);
    }
}

// ---------------- launch ----------------
extern "C" void kernel_launch(void* const* d_in, const int* in_sizes, int n_in,
                              void* d_out, int out_size, void* d_ws, size_t ws_size,
                              hipStream_t stream) {
    const float* x    = (const float*)d_in[0];
    const float* eWih = (const float*)d_in[1];
    const float* eWhh = (const float*)d_in[2];
    const float* ebih = (const float*)d_in[3];
    const float* ebhh = (const float*)d_in[4];
    const float* dWih = (const float*)d_in[5];
    const float* dWhh = (const float*)d_in[6];
    const float* dbih = (const float*)d_in[7];
    const float* dbhh = (const float*)d_in[8];
    const float* qW   = (const float*)d_in[9];
    const float* qb   = (const float*)d_in[10];
    const float* mW   = (const float*)d_in[11];
    const float* mb   = (const float*)d_in[12];
    const float* pW   = (const float*)d_in[13];
    const float* pb   = (const float*)d_in[14];
    const float* tW   = (const float*)d_in[15];
    const float* tb   = (const float*)d_in[16];
    float* out = (float*)d_out;

    char* w = (char*)d_ws;
    auto alloc = [&](size_t bytes) -> char* {
        char* p = w; w += (bytes + 255) & ~(size_t)255; return p;
    };
    // total ~76 MB
    float* Wc    = (float*)alloc((size_t)G3 * D * 4);
    float* W0    = (float*)alloc((size_t)G3 * 4);
    __hip_bfloat16* encB = (__hip_bfloat16*)alloc((size_t)BS * SEQ * D * 2);
    __hip_bfloat16* memB = (__hip_bfloat16*)alloc((size_t)BS * SEQ * D * 2);
    __hip_bfloat16* giB  = (__hip_bfloat16*)alloc((size_t)TCH * G3 * 64 * 2);
    float* hE0   = (float*)alloc((size_t)D * 64 * 4);
    float* hE1   = (float*)alloc((size_t)D * 64 * 4);
    float* hD0   = (float*)alloc((size_t)D * 64 * 4);
    float* hD1   = (float*)alloc((size_t)D * 64 * 4);
    float* qT    = (float*)alloc((size_t)BS * D * 4);
    float* ctxP  = (float*)alloc((size_t)2 * D * 64 * 4);
    float* seP   = (float*)alloc(2 * 64 * 4);
    float* lastP = (float*)alloc((TDEC + 1) * 64 * 4);

    kPrep<<<512, 256, 0, stream>>>(dWih, tb, Wc, W0, hE0, hD0, lastP, out);

    for (int c = 0; c < SEQ / TCH; ++c) {
        kGi<<<dim3(36, TCH), 256, 0, stream>>>(x, eWih, giB, c * TCH);
        for (int tc = 0; tc < TCH; ++tc) {
            const int t = c * TCH + tc;
            const float* hr = (t & 1) ? hE1 : hE0;
            float*       hw = (t & 1) ? hE0 : hE1;
            kEncStep2<<<192, 256, 0, stream>>>(giB + (size_t)tc * G3 * 64, eWhh,
                                               ebih, ebhh, hr, hw, encB, t);
        }
    }

    kGemmMem<<<dim3(12, 300), 256, 0, stream>>>(encB, mW, mb, memB);

    for (int t = 0; t < TDEC; ++t) {
        const float* hr = (t & 1) ? hD1 : hD0;
        float*       hw = (t & 1) ? hD0 : hD1;
        kQ<<<192, 256, 0, stream>>>(qW, qb, hr, qT);
        kAttn<<<128, 1024, 0, stream>>>(qT, memB, encB, pW, pb, ctxP, seP);
        kCell<<<192, 256, 0, stream>>>(Wc, W0, dWhh, dbih, dbhh, tW, ctxP, seP,
                                       lastP + t * 64, lastP + (t + 1) * 64,
                                       hr, hw, out, t);
    }
}